// Round 1
// baseline (939.377 us; speedup 1.0000x reference)
//
#include <hip/hip_runtime.h>
#include <hip/hip_bf16.h>

typedef __attribute__((ext_vector_type(8))) short short8;
typedef __attribute__((ext_vector_type(4))) float floatx4;

#define NB 4
#define GRIDD 128
#define GRID3 (128*128*128)
#define C 128
#define KSLOT 32

static __device__ __forceinline__ unsigned short f2bf(float f){
  unsigned u = __builtin_bit_cast(unsigned, f);
  unsigned r = (u + 0x7FFFu + ((u >> 16) & 1u)) >> 16;
  return (unsigned short)r;
}
static __device__ __forceinline__ float bf2f(unsigned short h){
  unsigned u = ((unsigned)h) << 16;
  return __builtin_bit_cast(float, u);
}

// ---------- prep: bf16 conversions + conv_w transpose + bottleneck fold ----------
__global__ void prepk(const float* __restrict__ feats, const float* __restrict__ convw,
                      const float* __restrict__ inw, const float* __restrict__ outw,
                      const float* __restrict__ bw,
                      unsigned short* __restrict__ Fb, unsigned short* __restrict__ Wt,
                      unsigned short* __restrict__ Wq, unsigned short* __restrict__ Wo,
                      unsigned short* __restrict__ Wc, long total1)
{
  const long stride = (long)gridDim.x * blockDim.x;
  const long i0 = (long)blockIdx.x * blockDim.x + threadIdx.x;
  for (long i = i0; i < total1; i += stride) Fb[i] = f2bf(feats[i]);
  // Wt[k][cout][cin] = convw[k][cin][cout]
  for (long i = i0; i < 27L*C*C; i += stride){
    long k = i >> 14; long r = (i >> 7) & 127; long c = i & 127;
    Wt[i] = f2bf(convw[(k << 14) + (c << 7) + r]);
  }
  for (long i = i0; i < C*C; i += stride){
    Wq[i] = f2bf(inw[i]);                 // rows 0..127 of in_proj_w
    Wo[i] = f2bf(outw[i]);
    long o = i >> 7, ci = i & 127;
    Wc[i] = f2bf(bw[o*256 + ci] + bw[o*256 + 128 + ci]);  // fold concat([a,a])@bw.T
  }
}

// ---------- scatter active sites into dense grid hash ----------
__global__ void scatterk(const int* __restrict__ coords, int* __restrict__ gh, int N){
  int p = blockIdx.x * 256 + threadIdx.x;
  if (p < N){
    int4 cr = *reinterpret_cast<const int4*>(coords + (size_t)p * 4);
    gh[(((cr.x*GRIDD + cr.y)*GRIDD + cr.z)*GRIDD) + cr.w] = p;
  }
}

// ---------- sparse 3^3 conv via MFMA with per-wave offset skipping ----------
__global__ __launch_bounds__(256) void convk(
    const unsigned short* __restrict__ F, const unsigned short* __restrict__ Wt,
    const int* __restrict__ coords, const int* __restrict__ gh,
    float* __restrict__ X, int N)
{
  const int tid = threadIdx.x;
  const int wave = tid >> 6, lane = tid & 63;
  const int rbase = blockIdx.x * 64 + wave * 16;   // wave tile: 16 rows x 128 cols
  const int lo = lane & 15, hi = lane >> 4;
  const int p = rbase + lo;
  const bool pv = p < N;
  int b = 0, x = 0, y = 0, z = 0;
  if (pv){
    const int4 cr = *reinterpret_cast<const int4*>(coords + (size_t)p * 4);
    b = cr.x; x = cr.y; y = cr.z; z = cr.w;
  }
  floatx4 acc[8];
  #pragma unroll
  for (int i = 0; i < 8; i++) acc[i] = (floatx4){0.f, 0.f, 0.f, 0.f};

  auto computeJ = [&](int k) -> int {
    const int dx = k / 9 - 1, dy = (k / 3) % 3 - 1, dz = k % 3 - 1;
    const int nx = x + dx, ny = y + dy, nz = z + dz;
    const bool ok = pv & (nx >= 0) & (nx < GRIDD) & (ny >= 0) & (ny < GRIDD)
                       & (nz >= 0) & (nz < GRIDD);
    const int gi = ((((b << 7) + (nx & 127)) << 7) + (ny & 127)) * GRIDD + (nz & 127);
    const int j = gh[gi];        // unconditional (gi always in-range), lets loads pipeline
    return ok ? j : -1;
  };

  int jcur = computeJ(0);
  for (int k = 0; k < 27; k++){
    const int jnext = (k < 26) ? computeJ(k + 1) : -1;   // prefetch next grid lookup
    if (__ballot(jcur >= 0) != 0ull){
      const int jc = jcur < 0 ? 0 : jcur;
      const unsigned short* frow = F + (size_t)jc * C;
      const unsigned short* wb = Wt + (size_t)k * C * C;
      #pragma unroll
      for (int kc = 0; kc < 4; kc++){
        const int koff = kc * 32 + hi * 8;
        short8 a = *reinterpret_cast<const short8*>(frow + koff);
        if (jcur < 0) a = (short8){0,0,0,0,0,0,0,0};
        #pragma unroll
        for (int ct = 0; ct < 8; ct++){
          const short8 bf = *reinterpret_cast<const short8*>(wb + (size_t)(ct*16 + lo)*C + koff);
          acc[ct] = __builtin_amdgcn_mfma_f32_16x16x32_bf16(a, bf, acc[ct], 0, 0, 0);
        }
      }
    }
    jcur = jnext;
  }
  #pragma unroll
  for (int ct = 0; ct < 8; ct++){
    const int col = ct * 16 + lo;
    #pragma unroll
    for (int i2 = 0; i2 < 4; i2++){
      const int row = rbase + hi * 4 + i2;
      if (row < N) X[(size_t)row * C + col] = acc[ct][i2];
    }
  }
}

// ---------- BN statistics ----------
__global__ __launch_bounds__(256) void bnstatsk(const float* __restrict__ X,
                                                float* __restrict__ sums,
                                                float* __restrict__ sumsq, int N){
  const int c = threadIdx.x & 127, rh = threadIdx.x >> 7;
  float s = 0.f, s2 = 0.f;
  for (int r = blockIdx.x * 2 + rh; r < N; r += gridDim.x * 2){
    float v = X[(size_t)r * C + c];
    s += v; s2 += v * v;
  }
  __shared__ float ls[256], ls2[256];
  ls[threadIdx.x] = s; ls2[threadIdx.x] = s2;
  __syncthreads();
  if (threadIdx.x < 128){
    atomicAdd(&sums[c], ls[c] + ls[c + 128]);
    atomicAdd(&sumsq[c], ls2[c] + ls2[c + 128]);
  }
}

// ---------- per-(batch,slot) softmax denominator over probs ----------
__global__ __launch_bounds__(256) void denomk(const float* __restrict__ probs,
                                              const int* __restrict__ coords,
                                              float* __restrict__ denom, int N){
  const int k = threadIdx.x & 31, rh = threadIdx.x >> 5;
  float a0 = 0.f, a1 = 0.f, a2 = 0.f, a3 = 0.f;
  for (int r = blockIdx.x * 8 + rh; r < N; r += gridDim.x * 8){
    const int b = coords[(size_t)r * 4];
    const float e = __expf(probs[(size_t)r * 32 + k]);
    a0 += (b == 0) ? e : 0.f;
    a1 += (b == 1) ? e : 0.f;
    a2 += (b == 2) ? e : 0.f;
    a3 += (b == 3) ? e : 0.f;
  }
  if (a0 != 0.f) atomicAdd(&denom[0*32 + k], a0);
  if (a1 != 0.f) atomicAdd(&denom[1*32 + k], a1);
  if (a2 != 0.f) atomicAdd(&denom[2*32 + k], a2);
  if (a3 != 0.f) atomicAdd(&denom[3*32 + k], a3);
}

// ---------- finalize BN scale/shift + inverse denominators ----------
__global__ void finalizek(const float* __restrict__ sums, const float* __restrict__ sumsq,
                          const float* __restrict__ gamma, const float* __restrict__ beta,
                          const float* __restrict__ denom,
                          float* __restrict__ scalev, float* __restrict__ shiftv,
                          float* __restrict__ invden, int N){
  const int t = threadIdx.x;   // 128
  const float invN = 1.f / (float)N;
  const float mu = sums[t] * invN;
  const float var = sumsq[t] * invN - mu * mu;
  const float sc = gamma[t] * rsqrtf(var + 1e-5f);
  scalev[t] = sc;
  shiftv[t] = beta[t] - mu * sc;
  invden[t] = 1.f / denom[t];
}

// ---------- BN apply + ReLU -> bf16 ----------
__global__ __launch_bounds__(256) void bnapplyk(const float* __restrict__ X,
                                                const float* __restrict__ scalev,
                                                const float* __restrict__ shiftv,
                                                unsigned short* __restrict__ Xb, long total){
  const long stride = (long)gridDim.x * blockDim.x;
  for (long i = (long)blockIdx.x * blockDim.x + threadIdx.x; i < total; i += stride){
    const int c = (int)(i & 127);
    float v = X[i] * scalev[c] + shiftv[c];
    v = fmaxf(v, 0.f);
    Xb[i] = f2bf(v);
  }
}

// ---------- ctx[b][k][c] = sum_n w[n,k] * x_bn[n,c] ----------
__global__ __launch_bounds__(256) void ctxk(const unsigned short* __restrict__ Xb,
                                            const float* __restrict__ probs,
                                            const int* __restrict__ coords,
                                            const float* __restrict__ invden,
                                            float* __restrict__ ctx, int N){
  __shared__ float wl[256 * 32];
  __shared__ int bl[256];
  const int n0 = blockIdx.x * 256;
  const int t = threadIdx.x;
  #pragma unroll
  for (int i = 0; i < 32; i++){
    const int flat = i * 256 + t;
    const int r = flat >> 5, k = flat & 31;
    const int n = n0 + r;
    float w = 0.f; int b = -1;
    if (n < N){
      b = coords[(size_t)n * 4];
      w = __expf(probs[(size_t)n * 32 + k]) * invden[b * 32 + k];
    }
    wl[r * 32 + k] = w;
    if (k == 0) bl[r] = b;
  }
  __syncthreads();
  const int c = t & 127, rh = t >> 7;
  float acc[32];
  #pragma unroll
  for (int k = 0; k < 32; k++) acc[k] = 0.f;
  int curb = -1; bool any = false;
  for (int r = rh; r < 256; r += 2){
    const int n = n0 + r;
    if (n >= N) break;
    const int bb = bl[r];
    if (bb != curb){
      if (any){
        #pragma unroll
        for (int k = 0; k < 32; k++){
          atomicAdd(&ctx[((size_t)curb * 32 + k) * C + c], acc[k]);
          acc[k] = 0.f;
        }
      }
      curb = bb; any = true;
    }
    const float xv = bf2f(Xb[(size_t)n * C + c]);
    const float4* wr = reinterpret_cast<const float4*>(&wl[r * 32]);
    #pragma unroll
    for (int kq = 0; kq < 8; kq++){
      const float4 w4 = wr[kq];
      acc[kq*4+0] = fmaf(w4.x, xv, acc[kq*4+0]);
      acc[kq*4+1] = fmaf(w4.y, xv, acc[kq*4+1]);
      acc[kq*4+2] = fmaf(w4.z, xv, acc[kq*4+2]);
      acc[kq*4+3] = fmaf(w4.w, xv, acc[kq*4+3]);
    }
  }
  if (any){
    #pragma unroll
    for (int k = 0; k < 32; k++) atomicAdd(&ctx[((size_t)curb * 32 + k) * C + c], acc[k]);
  }
}

// ---------- kh/vh = ctx @ Wk.T + bk / ctx @ Wv.T + bv ----------
__global__ __launch_bounds__(256) void kvk(const float* __restrict__ ctx,
                                           const float* __restrict__ inw,
                                           const float* __restrict__ inb,
                                           float* __restrict__ kh, float* __restrict__ vh){
  __shared__ float row[C];
  const int bk = blockIdx.x;          // b*32 + k
  const int t = threadIdx.x;
  if (t < C) row[t] = ctx[(size_t)bk * C + t];
  __syncthreads();
  const int cout = t & 127;
  const int which = t >> 7;           // 0 -> K, 1 -> V
  const float* W = inw + (size_t)(which ? 2 : 1) * C * C + (size_t)cout * C;
  float s = inb[(which ? 2 : 1) * C + cout];
  #pragma unroll 8
  for (int i = 0; i < C; i++) s = fmaf(row[i], W[i], s);
  (which ? vh : kh)[(size_t)bk * C + cout] = s;
}

// ---------- generic N x 128 @ (128x128)^T bf16 MFMA GEMM w/ bias, scale ----------
__global__ __launch_bounds__(256) void gemm128(
    const unsigned short* __restrict__ A, const unsigned short* __restrict__ W,
    const float* __restrict__ bias, float scale,
    float* __restrict__ outF, unsigned short* __restrict__ outB, int N)
{
  const int tid = threadIdx.x;
  const int wave = tid >> 6, lane = tid & 63;
  const int rbase = blockIdx.x * 64 + (wave >> 1) * 32;   // wave: 32 rows x 64 cols
  const int cbase = (wave & 1) * 64;
  const int lo = lane & 15, hi = lane >> 4;
  floatx4 acc[2][4];
  #pragma unroll
  for (int rt = 0; rt < 2; rt++)
    #pragma unroll
    for (int ct = 0; ct < 4; ct++) acc[rt][ct] = (floatx4){0.f,0.f,0.f,0.f};
  const int m0 = rbase + lo, m1 = rbase + 16 + lo;
  const int m0c = m0 < N ? m0 : N - 1;
  const int m1c = m1 < N ? m1 : N - 1;
  #pragma unroll
  for (int kc = 0; kc < 4; kc++){
    const int koff = kc * 32 + hi * 8;
    const short8 a0 = *reinterpret_cast<const short8*>(A + (size_t)m0c * C + koff);
    const short8 a1 = *reinterpret_cast<const short8*>(A + (size_t)m1c * C + koff);
    #pragma unroll
    for (int ct = 0; ct < 4; ct++){
      const int n = cbase + ct * 16 + lo;
      const short8 b = *reinterpret_cast<const short8*>(W + (size_t)n * C + koff);
      acc[0][ct] = __builtin_amdgcn_mfma_f32_16x16x32_bf16(a0, b, acc[0][ct], 0, 0, 0);
      acc[1][ct] = __builtin_amdgcn_mfma_f32_16x16x32_bf16(a1, b, acc[1][ct], 0, 0, 0);
    }
  }
  #pragma unroll
  for (int rt = 0; rt < 2; rt++){
    #pragma unroll
    for (int ct = 0; ct < 4; ct++){
      const int col = cbase + ct * 16 + lo;
      const float bv = bias ? bias[col] : 0.f;
      #pragma unroll
      for (int i = 0; i < 4; i++){
        const int row = rbase + rt * 16 + hi * 4 + i;
        if (row < N){
          const float v = (acc[rt][ct][i] + bv) * scale;
          if (outF) outF[(size_t)row * C + col] = v;
          if (outB) outB[(size_t)row * C + col] = f2bf(v);
        }
      }
    }
  }
}

// ---------- attention: scores -> softmax -> o  (one wave per point) ----------
__global__ __launch_bounds__(256) void attnk(const float* __restrict__ q,
                                             const float* __restrict__ kh,
                                             const float* __restrict__ vh,
                                             const int* __restrict__ coords,
                                             unsigned short* __restrict__ ob, int N){
  __shared__ float ql[4 * C];
  __shared__ float sl[4 * 256];
  __shared__ float inv[32];
  __shared__ int bbs[4];
  const int t = threadIdx.x;
  const int p0 = blockIdx.x * 4;
  #pragma unroll
  for (int i = 0; i < 2; i++){
    const int flat = i * 256 + t;
    const int p = flat >> 7, c = flat & 127;
    const int n = p0 + p;
    ql[flat] = (n < N) ? q[(size_t)n * C + c] : 0.f;
  }
  if (t < 4) bbs[t] = (p0 + t < N) ? coords[(size_t)(p0 + t) * 4] : 0;
  __syncthreads();
  #pragma unroll
  for (int i = 0; i < 4; i++){
    const int flat = i * 256 + t;
    const int p = flat >> 8, rem = flat & 255, h = rem >> 5, k = rem & 31;
    const float* qp = ql + p * C + h * 16;
    const float* kp = kh + ((size_t)bbs[p] * KSLOT + k) * C + h * 16;
    float s = 0.f;
    #pragma unroll
    for (int d = 0; d < 16; d++) s = fmaf(qp[d], kp[d], s);
    sl[flat] = s;
  }
  __syncthreads();
  if (t < 32){
    const int p = t >> 3, h = t & 7;
    float* s = sl + p * 256 + h * 32;
    float mx = s[0];
    #pragma unroll
    for (int k = 1; k < 32; k++) mx = fmaxf(mx, s[k]);
    float sum = 0.f;
    #pragma unroll
    for (int k = 0; k < 32; k++){ const float e = __expf(s[k] - mx); s[k] = e; sum += e; }
    inv[t] = 1.f / sum;
  }
  __syncthreads();
  #pragma unroll
  for (int i = 0; i < 2; i++){
    const int flat = i * 256 + t;
    const int p = flat >> 7, c = flat & 127, h = c >> 4;
    const int n = p0 + p;
    if (n >= N) continue;
    const float* vp = vh + (size_t)bbs[p] * KSLOT * C;
    const float* sp = sl + p * 256 + h * 32;
    float o = 0.f;
    #pragma unroll
    for (int k = 0; k < 32; k++) o = fmaf(sp[k], vp[(size_t)k * C + c], o);
    ob[(size_t)n * C + c] = f2bf(o * inv[p * 8 + h]);
  }
}

extern "C" void kernel_launch(void* const* d_in, const int* in_sizes, int n_in,
                              void* d_out, int out_size, void* d_ws, size_t ws_size,
                              hipStream_t stream){
  const float* feats  = (const float*)d_in[0];
  const float* probs  = (const float*)d_in[1];
  const float* convw  = (const float*)d_in[2];
  const float* gamma  = (const float*)d_in[3];
  const float* beta   = (const float*)d_in[4];
  const float* inw    = (const float*)d_in[5];
  const float* inb    = (const float*)d_in[6];
  const float* outw   = (const float*)d_in[7];
  const float* outb   = (const float*)d_in[8];
  const float* bw     = (const float*)d_in[9];
  const int*   coords = (const int*)d_in[10];
  const int N = in_sizes[0] / C;

  char* ws = (char*)d_ws;
  size_t off = 0;
  auto alloc = [&](size_t bytes) -> char* {
    char* r = ws + off; off += (bytes + 255) & ~(size_t)255; return r;
  };
  int* grid_h            = (int*)alloc((size_t)NB * GRID3 * 4);          // 33.5 MB
  unsigned short* featsb = (unsigned short*)alloc((size_t)N * C * 2);    // 25.6 MB
  unsigned short* convwt = (unsigned short*)alloc((size_t)27 * C * C * 2);
  unsigned short* wq     = (unsigned short*)alloc((size_t)C * C * 2);
  unsigned short* wo     = (unsigned short*)alloc((size_t)C * C * 2);
  unsigned short* wc     = (unsigned short*)alloc((size_t)C * C * 2);
  float* xconv           = (float*)alloc((size_t)N * C * 4);             // reused as q
  unsigned short* xbnb   = (unsigned short*)alloc((size_t)N * C * 2);
  float* zero_base       = (float*)alloc((size_t)(384 + NB*KSLOT*C) * 4);
  float* sums   = zero_base;
  float* sumsq  = zero_base + 128;
  float* denom  = zero_base + 256;
  float* ctx    = zero_base + 384;
  float* invden = (float*)alloc(512);
  float* scalev = (float*)alloc(512);
  float* shiftv = (float*)alloc(512);
  float* kh     = (float*)alloc((size_t)NB * KSLOT * C * 4);
  float* vh     = (float*)alloc((size_t)NB * KSLOT * C * 4);
  // buffer reuse (lifetimes disjoint):
  unsigned short* o_bf    = featsb;                 // feats_bf dead after convk
  unsigned short* attn_bf = (unsigned short*)grid_h;// grid dead after convk
  float* qbuf = xconv;                              // xconv dead after bnapplyk

  const long total1 = (long)N * C;
  hipMemsetAsync(grid_h, 0xFF, (size_t)NB * GRID3 * 4, stream);
  hipMemsetAsync(zero_base, 0, (size_t)(384 + NB*KSLOT*C) * 4, stream);
  prepk<<<2048, 256, 0, stream>>>(feats, convw, inw, outw, bw, featsb, convwt, wq, wo, wc, total1);
  scatterk<<<(N + 255) / 256, 256, 0, stream>>>(coords, grid_h, N);
  convk<<<(N + 63) / 64, 256, 0, stream>>>(featsb, convwt, coords, grid_h, xconv, N);
  bnstatsk<<<256, 256, 0, stream>>>(xconv, sums, sumsq, N);
  denomk<<<256, 256, 0, stream>>>(probs, coords, denom, N);
  finalizek<<<1, 128, 0, stream>>>(sums, sumsq, gamma, beta, denom, scalev, shiftv, invden, N);
  bnapplyk<<<1024, 256, 0, stream>>>(xconv, scalev, shiftv, xbnb, total1);
  ctxk<<<(N + 255) / 256, 256, 0, stream>>>(xbnb, probs, coords, invden, ctx, N);
  kvk<<<NB * KSLOT, 256, 0, stream>>>(ctx, inw, inb, kh, vh);
  gemm128<<<(N + 63) / 64, 256, 0, stream>>>(xbnb, wq, inb, 0.25f, qbuf, nullptr, N);
  attnk<<<(N + 3) / 4, 256, 0, stream>>>(qbuf, kh, vh, coords, o_bf, N);
  gemm128<<<(N + 63) / 64, 256, 0, stream>>>(o_bf, wo, outb, 1.f, nullptr, attn_bf, N);
  gemm128<<<(N + 63) / 64, 256, 0, stream>>>(attn_bf, wc, nullptr, 1.f, (float*)d_out, nullptr, N);
}

// Round 2
// 886.401 us; speedup vs baseline: 1.0598x; 1.0598x over previous
//
#include <hip/hip_runtime.h>
#include <hip/hip_bf16.h>

typedef __attribute__((ext_vector_type(8))) short short8;
typedef __attribute__((ext_vector_type(4))) float floatx4;

#define NB 4
#define GRIDD 128
#define GRID3 (128*128*128)
#define C 128
#define KSLOT 32

static __device__ __forceinline__ unsigned short f2bf(float f){
  unsigned u = __builtin_bit_cast(unsigned, f);
  unsigned r = (u + 0x7FFFu + ((u >> 16) & 1u)) >> 16;
  return (unsigned short)r;
}
static __device__ __forceinline__ float bf2f(unsigned short h){
  unsigned u = ((unsigned)h) << 16;
  return __builtin_bit_cast(float, u);
}

// ---------- prep: bf16 conversions + conv_w transpose ----------
__global__ void prepk(const float* __restrict__ feats, const float* __restrict__ convw,
                      const float* __restrict__ inw,
                      unsigned short* __restrict__ Fb, unsigned short* __restrict__ Wt,
                      unsigned short* __restrict__ Wq, long total1)
{
  const long stride = (long)gridDim.x * blockDim.x;
  const long i0 = (long)blockIdx.x * blockDim.x + threadIdx.x;
  for (long i = i0; i < total1; i += stride) Fb[i] = f2bf(feats[i]);
  // Wt[k][cout][cin] = convw[k][cin][cout]
  for (long i = i0; i < 27L*C*C; i += stride){
    long k = i >> 14; long r = (i >> 7) & 127; long c = i & 127;
    Wt[i] = f2bf(convw[(k << 14) + (c << 7) + r]);
  }
  for (long i = i0; i < C*C; i += stride) Wq[i] = f2bf(inw[i]);
}

// ---------- fold W2 = (bw[:, :128]+bw[:, 128:]) @ outw ; b2 = Wcf @ outb ----------
__global__ __launch_bounds__(128) void w2k(const float* __restrict__ bw,
                                           const float* __restrict__ outw,
                                           const float* __restrict__ outb,
                                           unsigned short* __restrict__ W2b,
                                           float* __restrict__ b2){
  const int o = blockIdx.x, i = threadIdx.x;   // 128 x 128
  __shared__ float wcf[128];
  __shared__ float red[128];
  const float w_i = bw[(size_t)o*256 + i] + bw[(size_t)o*256 + 128 + i];
  wcf[i] = w_i;
  red[i] = w_i * outb[i];
  __syncthreads();
  float acc = 0.f;
  #pragma unroll 8
  for (int j = 0; j < 128; j++) acc = fmaf(wcf[j], outw[j*128 + i], acc);
  W2b[o*128 + i] = f2bf(acc);
  for (int s = 64; s > 0; s >>= 1){
    if (i < s) red[i] += red[i + s];
    __syncthreads();
  }
  if (i == 0) b2[o] = red[0];
}

// ---------- scatter active sites into dense grid hash ----------
__global__ void scatterk(const int* __restrict__ coords, int* __restrict__ gh, int N){
  int p = blockIdx.x * 256 + threadIdx.x;
  if (p < N){
    int4 cr = *reinterpret_cast<const int4*>(coords + (size_t)p * 4);
    gh[(((cr.x*GRIDD + cr.y)*GRIDD + cr.z)*GRIDD) + cr.w] = p;
  }
}

// ---------- sparse 3^3 conv via MFMA with per-wave offset skipping ----------
__global__ __launch_bounds__(256) void convk(
    const unsigned short* __restrict__ F, const unsigned short* __restrict__ Wt,
    const int* __restrict__ coords, const int* __restrict__ gh,
    float* __restrict__ X, int N)
{
  const int tid = threadIdx.x;
  const int wave = tid >> 6, lane = tid & 63;
  const int rbase = blockIdx.x * 64 + wave * 16;   // wave tile: 16 rows x 128 cols
  const int lo = lane & 15, hi = lane >> 4;
  const int p = rbase + lo;
  const bool pv = p < N;
  int b = 0, x = 0, y = 0, z = 0;
  if (pv){
    const int4 cr = *reinterpret_cast<const int4*>(coords + (size_t)p * 4);
    b = cr.x; x = cr.y; y = cr.z; z = cr.w;
  }
  floatx4 acc[8];
  #pragma unroll
  for (int i = 0; i < 8; i++) acc[i] = (floatx4){0.f, 0.f, 0.f, 0.f};

  auto computeJ = [&](int k) -> int {
    const int dx = k / 9 - 1, dy = (k / 3) % 3 - 1, dz = k % 3 - 1;
    const int nx = x + dx, ny = y + dy, nz = z + dz;
    const bool ok = pv & (nx >= 0) & (nx < GRIDD) & (ny >= 0) & (ny < GRIDD)
                       & (nz >= 0) & (nz < GRIDD);
    const int gi = ((((b << 7) + (nx & 127)) << 7) + (ny & 127)) * GRIDD + (nz & 127);
    const int j = gh[gi];
    return ok ? j : -1;
  };

  int jcur = computeJ(0);
  for (int k = 0; k < 27; k++){
    const int jnext = (k < 26) ? computeJ(k + 1) : -1;
    if (__ballot(jcur >= 0) != 0ull){
      const int jc = jcur < 0 ? 0 : jcur;
      const unsigned short* frow = F + (size_t)jc * C;
      const unsigned short* wb = Wt + (size_t)k * C * C;
      #pragma unroll
      for (int kc = 0; kc < 4; kc++){
        const int koff = kc * 32 + hi * 8;
        short8 a = *reinterpret_cast<const short8*>(frow + koff);
        if (jcur < 0) a = (short8){0,0,0,0,0,0,0,0};
        #pragma unroll
        for (int ct = 0; ct < 8; ct++){
          const short8 bf = *reinterpret_cast<const short8*>(wb + (size_t)(ct*16 + lo)*C + koff);
          acc[ct] = __builtin_amdgcn_mfma_f32_16x16x32_bf16(a, bf, acc[ct], 0, 0, 0);
        }
      }
    }
    jcur = jnext;
  }
  #pragma unroll
  for (int ct = 0; ct < 8; ct++){
    const int col = ct * 16 + lo;
    #pragma unroll
    for (int i2 = 0; i2 < 4; i2++){
      const int row = rbase + hi * 4 + i2;
      if (row < N) X[(size_t)row * C + col] = acc[ct][i2];
    }
  }
}

// ---------- BN statistics ----------
__global__ __launch_bounds__(256) void bnstatsk(const float* __restrict__ X,
                                                float* __restrict__ sums,
                                                float* __restrict__ sumsq, int N){
  const int c = threadIdx.x & 127, rh = threadIdx.x >> 7;
  float s = 0.f, s2 = 0.f;
  for (int r = blockIdx.x * 2 + rh; r < N; r += gridDim.x * 2){
    float v = X[(size_t)r * C + c];
    s += v; s2 += v * v;
  }
  __shared__ float ls[256], ls2[256];
  ls[threadIdx.x] = s; ls2[threadIdx.x] = s2;
  __syncthreads();
  if (threadIdx.x < 128){
    atomicAdd(&sums[c], ls[c] + ls[c + 128]);
    atomicAdd(&sumsq[c], ls2[c] + ls2[c + 128]);
  }
}

// ---------- per-(batch,slot) softmax denominator over probs ----------
__global__ __launch_bounds__(256) void denomk(const float* __restrict__ probs,
                                              const int* __restrict__ coords,
                                              float* __restrict__ denom, int N){
  const int k = threadIdx.x & 31, rh = threadIdx.x >> 5;
  float a0 = 0.f, a1 = 0.f, a2 = 0.f, a3 = 0.f;
  for (int r = blockIdx.x * 8 + rh; r < N; r += gridDim.x * 8){
    const int b = coords[(size_t)r * 4];
    const float e = __expf(probs[(size_t)r * 32 + k]);
    a0 += (b == 0) ? e : 0.f;
    a1 += (b == 1) ? e : 0.f;
    a2 += (b == 2) ? e : 0.f;
    a3 += (b == 3) ? e : 0.f;
  }
  if (a0 != 0.f) atomicAdd(&denom[0*32 + k], a0);
  if (a1 != 0.f) atomicAdd(&denom[1*32 + k], a1);
  if (a2 != 0.f) atomicAdd(&denom[2*32 + k], a2);
  if (a3 != 0.f) atomicAdd(&denom[3*32 + k], a3);
}

// ---------- finalize BN scale/shift + inverse denominators ----------
__global__ void finalizek(const float* __restrict__ sums, const float* __restrict__ sumsq,
                          const float* __restrict__ gamma, const float* __restrict__ beta,
                          const float* __restrict__ denom,
                          float* __restrict__ scalev, float* __restrict__ shiftv,
                          float* __restrict__ invden, int N){
  const int t = threadIdx.x;   // 128
  const float invN = 1.f / (float)N;
  const float mu = sums[t] * invN;
  const float var = sumsq[t] * invN - mu * mu;
  const float sc = gamma[t] * rsqrtf(var + 1e-5f);
  scalev[t] = sc;
  shiftv[t] = beta[t] - mu * sc;
  invden[t] = 1.f / denom[t];
}

// ---------- BN apply + ReLU -> bf16 ----------
__global__ __launch_bounds__(256) void bnapplyk(const float* __restrict__ X,
                                                const float* __restrict__ scalev,
                                                const float* __restrict__ shiftv,
                                                unsigned short* __restrict__ Xb, long total){
  const long stride = (long)gridDim.x * blockDim.x;
  for (long i = (long)blockIdx.x * blockDim.x + threadIdx.x; i < total; i += stride){
    const int c = (int)(i & 127);
    float v = X[i] * scalev[c] + shiftv[c];
    v = fmaxf(v, 0.f);
    Xb[i] = f2bf(v);
  }
}

// ---------- ctx[b][k][c] = sum_n w[n,k] * x_bn[n,c] ----------
__global__ __launch_bounds__(256) void ctxk(const unsigned short* __restrict__ Xb,
                                            const float* __restrict__ probs,
                                            const int* __restrict__ coords,
                                            const float* __restrict__ invden,
                                            float* __restrict__ ctx, int N){
  __shared__ float wl[256 * 32];
  __shared__ int bl[256];
  const int n0 = blockIdx.x * 256;
  const int t = threadIdx.x;
  #pragma unroll
  for (int i = 0; i < 32; i++){
    const int flat = i * 256 + t;
    const int r = flat >> 5, k = flat & 31;
    const int n = n0 + r;
    float w = 0.f; int b = -1;
    if (n < N){
      b = coords[(size_t)n * 4];
      w = __expf(probs[(size_t)n * 32 + k]) * invden[b * 32 + k];
    }
    wl[r * 32 + k] = w;
    if (k == 0) bl[r] = b;
  }
  __syncthreads();
  const int c = t & 127, rh = t >> 7;
  float acc[32];
  #pragma unroll
  for (int k = 0; k < 32; k++) acc[k] = 0.f;
  int curb = -1; bool any = false;
  for (int r = rh; r < 256; r += 2){
    const int n = n0 + r;
    if (n >= N) break;
    const int bb = bl[r];
    if (bb != curb){
      if (any){
        #pragma unroll
        for (int k = 0; k < 32; k++){
          atomicAdd(&ctx[((size_t)curb * 32 + k) * C + c], acc[k]);
          acc[k] = 0.f;
        }
      }
      curb = bb; any = true;
    }
    const float xv = bf2f(Xb[(size_t)n * C + c]);
    const float4* wr = reinterpret_cast<const float4*>(&wl[r * 32]);
    #pragma unroll
    for (int kq = 0; kq < 8; kq++){
      const float4 w4 = wr[kq];
      acc[kq*4+0] = fmaf(w4.x, xv, acc[kq*4+0]);
      acc[kq*4+1] = fmaf(w4.y, xv, acc[kq*4+1]);
      acc[kq*4+2] = fmaf(w4.z, xv, acc[kq*4+2]);
      acc[kq*4+3] = fmaf(w4.w, xv, acc[kq*4+3]);
    }
  }
  if (any){
    #pragma unroll
    for (int k = 0; k < 32; k++) atomicAdd(&ctx[((size_t)curb * 32 + k) * C + c], acc[k]);
  }
}

// ---------- kh/vh = ctx @ Wk.T + bk / ctx @ Wv.T + bv ----------
__global__ __launch_bounds__(256) void kvk(const float* __restrict__ ctx,
                                           const float* __restrict__ inw,
                                           const float* __restrict__ inb,
                                           float* __restrict__ kh, float* __restrict__ vh){
  __shared__ float row[C];
  const int bk = blockIdx.x;          // b*32 + k
  const int t = threadIdx.x;
  if (t < C) row[t] = ctx[(size_t)bk * C + t];
  __syncthreads();
  const int cout = t & 127;
  const int which = t >> 7;           // 0 -> K, 1 -> V
  const float* W = inw + (size_t)(which ? 2 : 1) * C * C + (size_t)cout * C;
  float s = inb[(which ? 2 : 1) * C + cout];
  #pragma unroll 8
  for (int i = 0; i < C; i++) s = fmaf(row[i], W[i], s);
  (which ? vh : kh)[(size_t)bk * C + cout] = s;
}

// ---------- generic N x 128 @ (128x128)^T bf16 MFMA GEMM w/ bias, scale ----------
__global__ __launch_bounds__(256) void gemm128(
    const unsigned short* __restrict__ A, const unsigned short* __restrict__ W,
    const float* __restrict__ bias, float scale,
    float* __restrict__ outF, unsigned short* __restrict__ outB, int N)
{
  const int tid = threadIdx.x;
  const int wave = tid >> 6, lane = tid & 63;
  const int rbase = blockIdx.x * 64 + (wave >> 1) * 32;   // wave: 32 rows x 64 cols
  const int cbase = (wave & 1) * 64;
  const int lo = lane & 15, hi = lane >> 4;
  floatx4 acc[2][4];
  #pragma unroll
  for (int rt = 0; rt < 2; rt++)
    #pragma unroll
    for (int ct = 0; ct < 4; ct++) acc[rt][ct] = (floatx4){0.f,0.f,0.f,0.f};
  const int m0 = rbase + lo, m1 = rbase + 16 + lo;
  const int m0c = m0 < N ? m0 : N - 1;
  const int m1c = m1 < N ? m1 : N - 1;
  #pragma unroll
  for (int kc = 0; kc < 4; kc++){
    const int koff = kc * 32 + hi * 8;
    const short8 a0 = *reinterpret_cast<const short8*>(A + (size_t)m0c * C + koff);
    const short8 a1 = *reinterpret_cast<const short8*>(A + (size_t)m1c * C + koff);
    #pragma unroll
    for (int ct = 0; ct < 4; ct++){
      const int n = cbase + ct * 16 + lo;
      const short8 b = *reinterpret_cast<const short8*>(W + (size_t)n * C + koff);
      acc[0][ct] = __builtin_amdgcn_mfma_f32_16x16x32_bf16(a0, b, acc[0][ct], 0, 0, 0);
      acc[1][ct] = __builtin_amdgcn_mfma_f32_16x16x32_bf16(a1, b, acc[1][ct], 0, 0, 0);
    }
  }
  #pragma unroll
  for (int rt = 0; rt < 2; rt++){
    #pragma unroll
    for (int ct = 0; ct < 4; ct++){
      const int col = cbase + ct * 16 + lo;
      const float bv = bias ? bias[col] : 0.f;
      #pragma unroll
      for (int i = 0; i < 4; i++){
        const int row = rbase + rt * 16 + hi * 4 + i;
        if (row < N){
          const float v = (acc[rt][ct][i] + bv) * scale;
          if (outF) outF[(size_t)row * C + col] = v;
          if (outB) outB[(size_t)row * C + col] = f2bf(v);
        }
      }
    }
  }
}

// ---------- fused attention v2: LDS-staged, conflict-free, all f32 ----------
// block: 256 threads, handles 64 rows of one batch (4 chunks of 16)
__global__ __launch_bounds__(256) void attn2k(const float* __restrict__ q,
                                              const float* __restrict__ kh,
                                              const float* __restrict__ vh,
                                              unsigned short* __restrict__ ob, int NPER){
  __shared__ float khT[128 * 32];            // rotated: [c][ (k + 5*(c>>4)) & 31 ]
  __shared__ float vhL[32 * 128];            // [k][c]
  __shared__ float qL[16 * 128];             // rotated within-head d
  __shared__ __align__(16) float PL[16 * 288];  // [p][h*36 + k]
  const int t = threadIdx.x;
  const int b = blockIdx.y;
  const int n0 = blockIdx.x * 64;            // row offset within batch
  const float* khb = kh + (size_t)b * KSLOT * C;
  const float* vhb = vh + (size_t)b * KSLOT * C;

  for (int i = t; i < 4096; i += 256){
    const int c = i & 127, k = i >> 7;
    khT[c * 32 + ((k + 5 * (c >> 4)) & 31)] = khb[(size_t)k * C + c];
    vhL[i] = vhb[i];
  }
  __syncthreads();

  for (int chunk = 0; chunk < 4; chunk++){
    const int base = n0 + chunk * 16;
    // stage q chunk (rotated)
    for (int i = t; i < 2048; i += 256){
      const int p = i >> 7, c = i & 127, h = c >> 4, d = c & 15;
      const int n = base + p;
      qL[p * 128 + h * 16 + ((d + 5 * h) & 15)] =
          (n < NPER) ? q[((size_t)b * NPER + n) * C + c] : 0.f;
    }
    __syncthreads();
    // phase A: scores + softmax -> PL
    #pragma unroll
    for (int iter = 0; iter < 2; iter++){
      const int u = iter * 256 + t;
      const int kq = u & 7, h = (u >> 3) & 7, pp = u >> 6;
      int ko[4];
      #pragma unroll
      for (int i = 0; i < 4; i++) ko[i] = (kq * 4 + i + 5 * h) & 31;
      float s0[4] = {0.f,0.f,0.f,0.f}, s1[4] = {0.f,0.f,0.f,0.f};
      const int qb0 = (pp * 2) * 128 + h * 16;
      const int qb1 = qb0 + 128;
      #pragma unroll
      for (int d = 0; d < 16; d++){
        const int cb = (h * 16 + d) * 32;
        const int qoff = (d + 5 * h) & 15;
        const float q0 = qL[qb0 + qoff];
        const float q1 = qL[qb1 + qoff];
        #pragma unroll
        for (int i = 0; i < 4; i++){
          const float kv = khT[cb + ko[i]];
          s0[i] = fmaf(q0, kv, s0[i]);
          s1[i] = fmaf(q1, kv, s1[i]);
        }
      }
      #pragma unroll
      for (int pi = 0; pi < 2; pi++){
        float* s = pi ? s1 : s0;
        float m = fmaxf(fmaxf(s[0], s[1]), fmaxf(s[2], s[3]));
        m = fmaxf(m, __shfl_xor(m, 1));
        m = fmaxf(m, __shfl_xor(m, 2));
        m = fmaxf(m, __shfl_xor(m, 4));
        float e0 = __expf(s[0] - m), e1 = __expf(s[1] - m);
        float e2 = __expf(s[2] - m), e3 = __expf(s[3] - m);
        float sum = e0 + e1 + e2 + e3;
        sum += __shfl_xor(sum, 1);
        sum += __shfl_xor(sum, 2);
        sum += __shfl_xor(sum, 4);
        const float inv = 1.f / sum;
        float4 pw = make_float4(e0 * inv, e1 * inv, e2 * inv, e3 * inv);
        *reinterpret_cast<float4*>(&PL[(pp * 2 + pi) * 288 + h * 36 + kq * 4]) = pw;
      }
    }
    __syncthreads();
    // phase B: o = P @ vh
    const int c = t & 127, ph = t >> 7, h2 = c >> 4;
    float o[8];
    #pragma unroll
    for (int pi = 0; pi < 8; pi++) o[pi] = 0.f;
    #pragma unroll
    for (int kq = 0; kq < 8; kq++){
      const float v0 = vhL[(kq * 4 + 0) * 128 + c];
      const float v1 = vhL[(kq * 4 + 1) * 128 + c];
      const float v2 = vhL[(kq * 4 + 2) * 128 + c];
      const float v3 = vhL[(kq * 4 + 3) * 128 + c];
      #pragma unroll
      for (int pi = 0; pi < 8; pi++){
        const float4 pw = *reinterpret_cast<const float4*>(
            &PL[(ph * 8 + pi) * 288 + h2 * 36 + kq * 4]);
        o[pi] = fmaf(pw.x, v0, fmaf(pw.y, v1, fmaf(pw.z, v2, fmaf(pw.w, v3, o[pi]))));
      }
    }
    #pragma unroll
    for (int pi = 0; pi < 8; pi++){
      const int n = base + ph * 8 + pi;
      if (n < NPER) ob[((size_t)b * NPER + n) * C + c] = f2bf(o[pi]);
    }
    __syncthreads();
  }
}

extern "C" void kernel_launch(void* const* d_in, const int* in_sizes, int n_in,
                              void* d_out, int out_size, void* d_ws, size_t ws_size,
                              hipStream_t stream){
  const float* feats  = (const float*)d_in[0];
  const float* probs  = (const float*)d_in[1];
  const float* convw  = (const float*)d_in[2];
  const float* gamma  = (const float*)d_in[3];
  const float* beta   = (const float*)d_in[4];
  const float* inw    = (const float*)d_in[5];
  const float* inb    = (const float*)d_in[6];
  const float* outw   = (const float*)d_in[7];
  const float* outb   = (const float*)d_in[8];
  const float* bw     = (const float*)d_in[9];
  const int*   coords = (const int*)d_in[10];
  const int N = in_sizes[0] / C;
  const int NPER = N / NB;

  char* ws = (char*)d_ws;
  size_t off = 0;
  auto alloc = [&](size_t bytes) -> char* {
    char* r = ws + off; off += (bytes + 255) & ~(size_t)255; return r;
  };
  int* grid_h            = (int*)alloc((size_t)NB * GRID3 * 4);          // 33.5 MB
  unsigned short* featsb = (unsigned short*)alloc((size_t)N * C * 2);    // 25.6 MB
  unsigned short* convwt = (unsigned short*)alloc((size_t)27 * C * C * 2);
  unsigned short* wq     = (unsigned short*)alloc((size_t)C * C * 2);
  unsigned short* w2b    = (unsigned short*)alloc((size_t)C * C * 2);
  float* b2              = (float*)alloc(512);
  float* xconv           = (float*)alloc((size_t)N * C * 4);             // reused as q
  unsigned short* xbnb   = (unsigned short*)alloc((size_t)N * C * 2);
  float* zero_base       = (float*)alloc((size_t)(384 + NB*KSLOT*C) * 4);
  float* sums   = zero_base;
  float* sumsq  = zero_base + 128;
  float* denom  = zero_base + 256;
  float* ctx    = zero_base + 384;
  float* invden = (float*)alloc(512);
  float* scalev = (float*)alloc(512);
  float* shiftv = (float*)alloc(512);
  float* kh     = (float*)alloc((size_t)NB * KSLOT * C * 4);
  float* vh     = (float*)alloc((size_t)NB * KSLOT * C * 4);
  // buffer reuse (lifetimes disjoint):
  unsigned short* o_bf = featsb;     // feats_bf dead after convk
  float* qbuf = xconv;               // xconv dead after bnapplyk

  const long total1 = (long)N * C;
  hipMemsetAsync(grid_h, 0xFF, (size_t)NB * GRID3 * 4, stream);
  hipMemsetAsync(zero_base, 0, (size_t)(384 + NB*KSLOT*C) * 4, stream);
  prepk<<<2048, 256, 0, stream>>>(feats, convw, inw, featsb, convwt, wq, total1);
  w2k<<<128, 128, 0, stream>>>(bw, outw, outb, w2b, b2);
  scatterk<<<(N + 255) / 256, 256, 0, stream>>>(coords, grid_h, N);
  convk<<<(N + 63) / 64, 256, 0, stream>>>(featsb, convwt, coords, grid_h, xconv, N);
  bnstatsk<<<256, 256, 0, stream>>>(xconv, sums, sumsq, N);
  denomk<<<256, 256, 0, stream>>>(probs, coords, denom, N);
  finalizek<<<1, 128, 0, stream>>>(sums, sumsq, gamma, beta, denom, scalev, shiftv, invden, N);
  bnapplyk<<<1024, 256, 0, stream>>>(xconv, scalev, shiftv, xbnb, total1);
  ctxk<<<(N + 255) / 256, 256, 0, stream>>>(xbnb, probs, coords, invden, ctx, N);
  kvk<<<NB * KSLOT, 256, 0, stream>>>(ctx, inw, inb, kh, vh);
  gemm128<<<(N + 63) / 64, 256, 0, stream>>>(xbnb, wq, inb, 0.25f, qbuf, nullptr, N);
  dim3 agrid((NPER + 63) / 64, NB);
  attn2k<<<agrid, 256, 0, stream>>>(qbuf, kh, vh, o_bf, NPER);
  gemm128<<<(N + 63) / 64, 256, 0, stream>>>(o_bf, w2b, b2, 1.f, (float*)d_out, nullptr, N);
}

// Round 3
// 708.027 us; speedup vs baseline: 1.3268x; 1.2519x over previous
//
#include <hip/hip_runtime.h>
#include <hip/hip_bf16.h>

typedef __attribute__((ext_vector_type(8))) short short8;
typedef __attribute__((ext_vector_type(4))) float floatx4;

#define NB 4
#define GRIDD 128
#define GRID3 (128*128*128)
#define C 128
#define KSLOT 32
#define CTX_BPB 128   // ctx partial blocks per batch

static __device__ __forceinline__ unsigned short f2bf(float f){
  unsigned u = __builtin_bit_cast(unsigned, f);
  unsigned r = (u + 0x7FFFu + ((u >> 16) & 1u)) >> 16;
  return (unsigned short)r;
}
static __device__ __forceinline__ float bf2f(unsigned short h){
  unsigned u = ((unsigned)h) << 16;
  return __builtin_bit_cast(float, u);
}

// ---------- prep: bf16 conversions + conv_w transpose ----------
__global__ void prepk(const float* __restrict__ feats, const float* __restrict__ convw,
                      const float* __restrict__ inw,
                      unsigned short* __restrict__ Fb, unsigned short* __restrict__ Wt,
                      unsigned short* __restrict__ Wq, long total1)
{
  const long stride = (long)gridDim.x * blockDim.x;
  const long i0 = (long)blockIdx.x * blockDim.x + threadIdx.x;
  for (long i = i0; i < total1; i += stride) Fb[i] = f2bf(feats[i]);
  // Wt[k][cout][cin] = convw[k][cin][cout]
  for (long i = i0; i < 27L*C*C; i += stride){
    long k = i >> 14; long r = (i >> 7) & 127; long c = i & 127;
    Wt[i] = f2bf(convw[(k << 14) + (c << 7) + r]);
  }
  for (long i = i0; i < C*C; i += stride) Wq[i] = f2bf(inw[i]);
}

// ---------- fold W2 = (bw[:, :128]+bw[:, 128:]) @ outw ; b2 = Wcf @ outb ----------
__global__ __launch_bounds__(128) void w2k(const float* __restrict__ bw,
                                           const float* __restrict__ outw,
                                           const float* __restrict__ outb,
                                           unsigned short* __restrict__ W2b,
                                           float* __restrict__ b2){
  const int o = blockIdx.x, i = threadIdx.x;   // 128 x 128
  __shared__ float wcf[128];
  __shared__ float red[128];
  const float w_i = bw[(size_t)o*256 + i] + bw[(size_t)o*256 + 128 + i];
  wcf[i] = w_i;
  red[i] = w_i * outb[i];
  __syncthreads();
  float acc = 0.f;
  #pragma unroll 8
  for (int j = 0; j < 128; j++) acc = fmaf(wcf[j], outw[j*128 + i], acc);
  W2b[o*128 + i] = f2bf(acc);
  for (int s = 64; s > 0; s >>= 1){
    if (i < s) red[i] += red[i + s];
    __syncthreads();
  }
  if (i == 0) b2[o] = red[0];
}

// ---------- scatter active sites into dense grid hash ----------
__global__ void scatterk(const int* __restrict__ coords, int* __restrict__ gh, int N){
  int p = blockIdx.x * 256 + threadIdx.x;
  if (p < N){
    int4 cr = *reinterpret_cast<const int4*>(coords + (size_t)p * 4);
    gh[(((cr.x*GRIDD + cr.y)*GRIDD + cr.z)*GRIDD) + cr.w] = p;
  }
}

// ---------- sparse 3^3 conv via MFMA with per-wave offset skipping ----------
__global__ __launch_bounds__(256) void convk(
    const unsigned short* __restrict__ F, const unsigned short* __restrict__ Wt,
    const int* __restrict__ coords, const int* __restrict__ gh,
    float* __restrict__ X, int N)
{
  const int tid = threadIdx.x;
  const int wave = tid >> 6, lane = tid & 63;
  const int rbase = blockIdx.x * 64 + wave * 16;   // wave tile: 16 rows x 128 cols
  const int lo = lane & 15, hi = lane >> 4;
  const int p = rbase + lo;
  const bool pv = p < N;
  int b = 0, x = 0, y = 0, z = 0;
  if (pv){
    const int4 cr = *reinterpret_cast<const int4*>(coords + (size_t)p * 4);
    b = cr.x; x = cr.y; y = cr.z; z = cr.w;
  }
  floatx4 acc[8];
  #pragma unroll
  for (int i = 0; i < 8; i++) acc[i] = (floatx4){0.f, 0.f, 0.f, 0.f};

  auto computeJ = [&](int k) -> int {
    const int dx = k / 9 - 1, dy = (k / 3) % 3 - 1, dz = k % 3 - 1;
    const int nx = x + dx, ny = y + dy, nz = z + dz;
    const bool ok = pv & (nx >= 0) & (nx < GRIDD) & (ny >= 0) & (ny < GRIDD)
                       & (nz >= 0) & (nz < GRIDD);
    const int gi = ((((b << 7) + (nx & 127)) << 7) + (ny & 127)) * GRIDD + (nz & 127);
    const int j = gh[gi];
    return ok ? j : -1;
  };

  int jcur = computeJ(0);
  for (int k = 0; k < 27; k++){
    const int jnext = (k < 26) ? computeJ(k + 1) : -1;
    if (__ballot(jcur >= 0) != 0ull){
      const int jc = jcur < 0 ? 0 : jcur;
      const unsigned short* frow = F + (size_t)jc * C;
      const unsigned short* wb = Wt + (size_t)k * C * C;
      #pragma unroll
      for (int kc = 0; kc < 4; kc++){
        const int koff = kc * 32 + hi * 8;
        short8 a = *reinterpret_cast<const short8*>(frow + koff);
        if (jcur < 0) a = (short8){0,0,0,0,0,0,0,0};
        #pragma unroll
        for (int ct = 0; ct < 8; ct++){
          const short8 bf = *reinterpret_cast<const short8*>(wb + (size_t)(ct*16 + lo)*C + koff);
          acc[ct] = __builtin_amdgcn_mfma_f32_16x16x32_bf16(a, bf, acc[ct], 0, 0, 0);
        }
      }
    }
    jcur = jnext;
  }
  #pragma unroll
  for (int ct = 0; ct < 8; ct++){
    const int col = ct * 16 + lo;
    #pragma unroll
    for (int i2 = 0; i2 < 4; i2++){
      const int row = rbase + hi * 4 + i2;
      if (row < N) X[(size_t)row * C + col] = acc[ct][i2];
    }
  }
}

// ---------- BN statistics ----------
__global__ __launch_bounds__(256) void bnstatsk(const float* __restrict__ X,
                                                float* __restrict__ sums,
                                                float* __restrict__ sumsq, int N){
  const int c = threadIdx.x & 127, rh = threadIdx.x >> 7;
  float s = 0.f, s2 = 0.f;
  for (int r = blockIdx.x * 2 + rh; r < N; r += gridDim.x * 2){
    float v = X[(size_t)r * C + c];
    s += v; s2 += v * v;
  }
  __shared__ float ls[256], ls2[256];
  ls[threadIdx.x] = s; ls2[threadIdx.x] = s2;
  __syncthreads();
  if (threadIdx.x < 128){
    atomicAdd(&sums[c], ls[c] + ls[c + 128]);
    atomicAdd(&sumsq[c], ls2[c] + ls2[c + 128]);
  }
}

// ---------- per-(batch,slot) softmax denominator + wexp store ----------
__global__ __launch_bounds__(256) void denomk(const float* __restrict__ probs,
                                              const int* __restrict__ coords,
                                              float* __restrict__ denom,
                                              float* __restrict__ wexp, int N){
  const int k = threadIdx.x & 31, rh = threadIdx.x >> 5;
  float a0 = 0.f, a1 = 0.f, a2 = 0.f, a3 = 0.f;
  for (int r = blockIdx.x * 8 + rh; r < N; r += gridDim.x * 8){
    const int b = coords[(size_t)r * 4];
    const float e = __expf(probs[(size_t)r * 32 + k]);
    wexp[(size_t)r * 32 + k] = e;
    a0 += (b == 0) ? e : 0.f;
    a1 += (b == 1) ? e : 0.f;
    a2 += (b == 2) ? e : 0.f;
    a3 += (b == 3) ? e : 0.f;
  }
  if (a0 != 0.f) atomicAdd(&denom[0*32 + k], a0);
  if (a1 != 0.f) atomicAdd(&denom[1*32 + k], a1);
  if (a2 != 0.f) atomicAdd(&denom[2*32 + k], a2);
  if (a3 != 0.f) atomicAdd(&denom[3*32 + k], a3);
}

// ---------- finalize BN scale/shift + inverse denominators ----------
__global__ void finalizek(const float* __restrict__ sums, const float* __restrict__ sumsq,
                          const float* __restrict__ gamma, const float* __restrict__ beta,
                          const float* __restrict__ denom,
                          float* __restrict__ scalev, float* __restrict__ shiftv,
                          float* __restrict__ invden, int N){
  const int t = threadIdx.x;   // 128
  const float invN = 1.f / (float)N;
  const float mu = sums[t] * invN;
  const float var = sumsq[t] * invN - mu * mu;
  const float sc = gamma[t] * rsqrtf(var + 1e-5f);
  scalev[t] = sc;
  shiftv[t] = beta[t] - mu * sc;
  invden[t] = 1.f / denom[t];
}

// ---------- BN apply + ReLU -> bf16 ----------
__global__ __launch_bounds__(256) void bnapplyk(const float* __restrict__ X,
                                                const float* __restrict__ scalev,
                                                const float* __restrict__ shiftv,
                                                unsigned short* __restrict__ Xb, long total){
  const long stride = (long)gridDim.x * blockDim.x;
  for (long i = (long)blockIdx.x * blockDim.x + threadIdx.x; i < total; i += stride){
    const int c = (int)(i & 127);
    float v = X[i] * scalev[c] + shiftv[c];
    v = fmaxf(v, 0.f);
    Xb[i] = f2bf(v);
  }
}

// ---------- ctx partials: pbuf[b*128+j][k][c] over 196-row strips ----------
__global__ __launch_bounds__(256) void ctx2k(const unsigned short* __restrict__ Xb,
                                             const float* __restrict__ wexp,
                                             float* __restrict__ pbuf, int NPER){
  const int blk = blockIdx.x;
  const int b = blk >> 7, j = blk & 127;
  const int rows = (NPER + CTX_BPB - 1) / CTX_BPB;
  const int r0 = j * rows;
  const int r1 = min(r0 + rows, NPER);
  const int t = threadIdx.x, c = t & 127, rh = t >> 7;
  float acc[KSLOT];
  #pragma unroll
  for (int k = 0; k < KSLOT; k++) acc[k] = 0.f;
  for (int r = r0 + rh; r < r1; r += 2){
    const size_t nn = (size_t)b * NPER + r;
    const float xv = bf2f(Xb[nn * C + c]);
    const float4* wr = reinterpret_cast<const float4*>(wexp + nn * KSLOT);
    #pragma unroll
    for (int kq = 0; kq < 8; kq++){
      const float4 w4 = wr[kq];
      acc[kq*4+0] = fmaf(w4.x, xv, acc[kq*4+0]);
      acc[kq*4+1] = fmaf(w4.y, xv, acc[kq*4+1]);
      acc[kq*4+2] = fmaf(w4.z, xv, acc[kq*4+2]);
      acc[kq*4+3] = fmaf(w4.w, xv, acc[kq*4+3]);
    }
  }
  __shared__ float red[2 * KSLOT * C];
  #pragma unroll
  for (int k = 0; k < KSLOT; k++) red[(rh * KSLOT + k) * C + c] = acc[k];
  __syncthreads();
  float* dst = pbuf + (size_t)blk * KSLOT * C;
  for (int i = t; i < KSLOT * C; i += 256) dst[i] = red[i] + red[KSLOT * C + i];
}

// ---------- reduce partials -> ctx (scaled by invden) ----------
__global__ __launch_bounds__(256) void reducek(const float* __restrict__ pbuf,
                                               const float* __restrict__ invden,
                                               float* __restrict__ ctx){
  const int i = blockIdx.x * 256 + threadIdx.x;   // 16384 total
  const int b = i >> 12, kc = i & 4095, k = kc >> 7;
  float s = 0.f;
  for (int j = 0; j < CTX_BPB; j++)
    s += pbuf[(size_t)(b * CTX_BPB + j) * (KSLOT * C) + kc];
  ctx[i] = s * invden[b * KSLOT + k];
}

// ---------- kh/vh = ctx @ Wk.T + bk / ctx @ Wv.T + bv ----------
__global__ __launch_bounds__(256) void kvk(const float* __restrict__ ctx,
                                           const float* __restrict__ inw,
                                           const float* __restrict__ inb,
                                           float* __restrict__ kh, float* __restrict__ vh){
  __shared__ float row[C];
  const int bk = blockIdx.x;          // b*32 + k
  const int t = threadIdx.x;
  if (t < C) row[t] = ctx[(size_t)bk * C + t];
  __syncthreads();
  const int cout = t & 127;
  const int which = t >> 7;           // 0 -> K, 1 -> V
  const float* W = inw + (size_t)(which ? 2 : 1) * C * C + (size_t)cout * C;
  float s = inb[(which ? 2 : 1) * C + cout];
  #pragma unroll 8
  for (int i = 0; i < C; i++) s = fmaf(row[i], W[i], s);
  (which ? vh : kh)[(size_t)bk * C + cout] = s;
}

// ---------- generic N x 128 @ (128x128)^T bf16 MFMA GEMM w/ bias, scale ----------
__global__ __launch_bounds__(256) void gemm128(
    const unsigned short* __restrict__ A, const unsigned short* __restrict__ W,
    const float* __restrict__ bias, float scale,
    float* __restrict__ outF, unsigned short* __restrict__ outB, int N)
{
  const int tid = threadIdx.x;
  const int wave = tid >> 6, lane = tid & 63;
  const int rbase = blockIdx.x * 64 + (wave >> 1) * 32;   // wave: 32 rows x 64 cols
  const int cbase = (wave & 1) * 64;
  const int lo = lane & 15, hi = lane >> 4;
  floatx4 acc[2][4];
  #pragma unroll
  for (int rt = 0; rt < 2; rt++)
    #pragma unroll
    for (int ct = 0; ct < 4; ct++) acc[rt][ct] = (floatx4){0.f,0.f,0.f,0.f};
  const int m0 = rbase + lo, m1 = rbase + 16 + lo;
  const int m0c = m0 < N ? m0 : N - 1;
  const int m1c = m1 < N ? m1 : N - 1;
  #pragma unroll
  for (int kc = 0; kc < 4; kc++){
    const int koff = kc * 32 + hi * 8;
    const short8 a0 = *reinterpret_cast<const short8*>(A + (size_t)m0c * C + koff);
    const short8 a1 = *reinterpret_cast<const short8*>(A + (size_t)m1c * C + koff);
    #pragma unroll
    for (int ct = 0; ct < 4; ct++){
      const int n = cbase + ct * 16 + lo;
      const short8 b = *reinterpret_cast<const short8*>(W + (size_t)n * C + koff);
      acc[0][ct] = __builtin_amdgcn_mfma_f32_16x16x32_bf16(a0, b, acc[0][ct], 0, 0, 0);
      acc[1][ct] = __builtin_amdgcn_mfma_f32_16x16x32_bf16(a1, b, acc[1][ct], 0, 0, 0);
    }
  }
  #pragma unroll
  for (int rt = 0; rt < 2; rt++){
    #pragma unroll
    for (int ct = 0; ct < 4; ct++){
      const int col = cbase + ct * 16 + lo;
      const float bv = bias ? bias[col] : 0.f;
      #pragma unroll
      for (int i = 0; i < 4; i++){
        const int row = rbase + rt * 16 + hi * 4 + i;
        if (row < N){
          const float v = (acc[rt][ct][i] + bv) * scale;
          if (outF) outF[(size_t)row * C + col] = v;
          if (outB) outB[(size_t)row * C + col] = f2bf(v);
        }
      }
    }
  }
}

// ---------- attention v3: thread owns (row, head); P stays in registers ----------
__global__ __launch_bounds__(256) void attn3k(const unsigned short* __restrict__ qb,
                                              const float* __restrict__ kh,
                                              const float* __restrict__ vh,
                                              unsigned short* __restrict__ ob, int NPER){
  __shared__ float khL[KSLOT * C];
  __shared__ float vhL[KSLOT * C];
  const int t = threadIdx.x;
  const int b = blockIdx.y;
  const int n0 = blockIdx.x * 32;
  {
    const float4* ks = reinterpret_cast<const float4*>(kh + (size_t)b * KSLOT * C);
    const float4* vs = reinterpret_cast<const float4*>(vh + (size_t)b * KSLOT * C);
    float4* kd = reinterpret_cast<float4*>(khL);
    float4* vd = reinterpret_cast<float4*>(vhL);
    #pragma unroll
    for (int i = 0; i < 4; i++){ kd[i * 256 + t] = ks[i * 256 + t]; vd[i * 256 + t] = vs[i * 256 + t]; }
  }
  __syncthreads();
  const int h = t >> 5, p = t & 31;
  const int n = n0 + p;
  const int nc = n < NPER ? n : NPER - 1;
  float qv[16];
  {
    const short8* qp = reinterpret_cast<const short8*>(qb + ((size_t)b * NPER + nc) * C + h * 16);
    const short8 qa = qp[0], qc = qp[1];
    #pragma unroll
    for (int i = 0; i < 8; i++){
      qv[i]     = bf2f((unsigned short)qa[i]);
      qv[8 + i] = bf2f((unsigned short)qc[i]);
    }
  }
  float sv[KSLOT];
  #pragma unroll
  for (int k = 0; k < KSLOT; k++){
    const float4* kp = reinterpret_cast<const float4*>(&khL[k * C + h * 16]);
    const float4 k0 = kp[0], k1 = kp[1], k2 = kp[2], k3 = kp[3];
    float s;
    s = qv[0] * k0.x;
    s = fmaf(qv[1], k0.y, s);  s = fmaf(qv[2],  k0.z, s);  s = fmaf(qv[3],  k0.w, s);
    s = fmaf(qv[4], k1.x, s);  s = fmaf(qv[5],  k1.y, s);  s = fmaf(qv[6],  k1.z, s);
    s = fmaf(qv[7], k1.w, s);  s = fmaf(qv[8],  k2.x, s);  s = fmaf(qv[9],  k2.y, s);
    s = fmaf(qv[10], k2.z, s); s = fmaf(qv[11], k2.w, s);  s = fmaf(qv[12], k3.x, s);
    s = fmaf(qv[13], k3.y, s); s = fmaf(qv[14], k3.z, s);  s = fmaf(qv[15], k3.w, s);
    sv[k] = s;
  }
  float m = sv[0];
  #pragma unroll
  for (int k = 1; k < KSLOT; k++) m = fmaxf(m, sv[k]);
  float sum = 0.f;
  #pragma unroll
  for (int k = 0; k < KSLOT; k++){ const float e = __expf(sv[k] - m); sv[k] = e; sum += e; }
  const float inv = 1.f / sum;
  float o[16];
  #pragma unroll
  for (int i = 0; i < 16; i++) o[i] = 0.f;
  #pragma unroll
  for (int k = 0; k < KSLOT; k++){
    const float w = sv[k];
    const float4* vp = reinterpret_cast<const float4*>(&vhL[k * C + h * 16]);
    const float4 v0 = vp[0], v1 = vp[1], v2 = vp[2], v3 = vp[3];
    o[0]  = fmaf(w, v0.x, o[0]);  o[1]  = fmaf(w, v0.y, o[1]);
    o[2]  = fmaf(w, v0.z, o[2]);  o[3]  = fmaf(w, v0.w, o[3]);
    o[4]  = fmaf(w, v1.x, o[4]);  o[5]  = fmaf(w, v1.y, o[5]);
    o[6]  = fmaf(w, v1.z, o[6]);  o[7]  = fmaf(w, v1.w, o[7]);
    o[8]  = fmaf(w, v2.x, o[8]);  o[9]  = fmaf(w, v2.y, o[9]);
    o[10] = fmaf(w, v2.z, o[10]); o[11] = fmaf(w, v2.w, o[11]);
    o[12] = fmaf(w, v3.x, o[12]); o[13] = fmaf(w, v3.y, o[13]);
    o[14] = fmaf(w, v3.z, o[14]); o[15] = fmaf(w, v3.w, o[15]);
  }
  if (n < NPER){
    short8 s0, s1;
    #pragma unroll
    for (int i = 0; i < 8; i++){
      s0[i] = (short)f2bf(o[i] * inv);
      s1[i] = (short)f2bf(o[8 + i] * inv);
    }
    unsigned short* op = ob + ((size_t)b * NPER + n) * C + h * 16;
    *reinterpret_cast<short8*>(op) = s0;
    *reinterpret_cast<short8*>(op + 8) = s1;
  }
}

extern "C" void kernel_launch(void* const* d_in, const int* in_sizes, int n_in,
                              void* d_out, int out_size, void* d_ws, size_t ws_size,
                              hipStream_t stream){
  const float* feats  = (const float*)d_in[0];
  const float* probs  = (const float*)d_in[1];
  const float* convw  = (const float*)d_in[2];
  const float* gamma  = (const float*)d_in[3];
  const float* beta   = (const float*)d_in[4];
  const float* inw    = (const float*)d_in[5];
  const float* inb    = (const float*)d_in[6];
  const float* outw   = (const float*)d_in[7];
  const float* outb   = (const float*)d_in[8];
  const float* bw     = (const float*)d_in[9];
  const int*   coords = (const int*)d_in[10];
  const int N = in_sizes[0] / C;
  const int NPER = N / NB;

  char* ws = (char*)d_ws;
  size_t off = 0;
  auto alloc = [&](size_t bytes) -> char* {
    char* r = ws + off; off += (bytes + 255) & ~(size_t)255; return r;
  };
  int* grid_h            = (int*)alloc((size_t)NB * GRID3 * 4);          // 33.5 MB
  unsigned short* featsb = (unsigned short*)alloc((size_t)N * C * 2);    // 25.6 MB
  unsigned short* convwt = (unsigned short*)alloc((size_t)27 * C * C * 2);
  unsigned short* wq     = (unsigned short*)alloc((size_t)C * C * 2);
  unsigned short* w2b    = (unsigned short*)alloc((size_t)C * C * 2);
  float* b2              = (float*)alloc(512);
  float* xconv           = (float*)alloc((size_t)N * C * 4);             // reused as qb
  unsigned short* xbnb   = (unsigned short*)alloc((size_t)N * C * 2);
  float* zero_base       = (float*)alloc((size_t)384 * 4);
  float* sums   = zero_base;
  float* sumsq  = zero_base + 128;
  float* denom  = zero_base + 256;
  float* ctx    = (float*)alloc((size_t)NB * KSLOT * C * 4);
  float* invden = (float*)alloc(512);
  float* scalev = (float*)alloc(512);
  float* shiftv = (float*)alloc(512);
  float* kh     = (float*)alloc((size_t)NB * KSLOT * C * 4);
  float* vh     = (float*)alloc((size_t)NB * KSLOT * C * 4);
  // buffer reuse (lifetimes disjoint):
  unsigned short* o_bf = featsb;                 // feats_bf dead after convk
  unsigned short* qb   = (unsigned short*)xconv; // xconv dead after bnapplyk
  float* wexp = (float*)grid_h;                  // grid dead after convk
  float* pbuf = wexp + (size_t)N * KSLOT;        // + 8 MB partials (fits in 33.5 MB)

  const long total1 = (long)N * C;
  hipMemsetAsync(grid_h, 0xFF, (size_t)NB * GRID3 * 4, stream);
  hipMemsetAsync(zero_base, 0, (size_t)384 * 4, stream);
  prepk<<<2048, 256, 0, stream>>>(feats, convw, inw, featsb, convwt, wq, total1);
  w2k<<<128, 128, 0, stream>>>(bw, outw, outb, w2b, b2);
  scatterk<<<(N + 255) / 256, 256, 0, stream>>>(coords, grid_h, N);
  convk<<<(N + 63) / 64, 256, 0, stream>>>(featsb, convwt, coords, grid_h, xconv, N);
  // grid_h dead from here; wexp/pbuf alias it
  bnstatsk<<<256, 256, 0, stream>>>(xconv, sums, sumsq, N);
  denomk<<<256, 256, 0, stream>>>(probs, coords, denom, wexp, N);
  finalizek<<<1, 128, 0, stream>>>(sums, sumsq, gamma, beta, denom, scalev, shiftv, invden, N);
  bnapplyk<<<1024, 256, 0, stream>>>(xconv, scalev, shiftv, xbnb, total1);
  // xconv dead from here; qb aliases it
  ctx2k<<<NB * CTX_BPB, 256, 0, stream>>>(xbnb, wexp, pbuf, NPER);
  reducek<<<64, 256, 0, stream>>>(pbuf, invden, ctx);
  kvk<<<NB * KSLOT, 256, 0, stream>>>(ctx, inw, inb, kh, vh);
  gemm128<<<(N + 63) / 64, 256, 0, stream>>>(xbnb, wq, inb, 0.25f, nullptr, qb, N);
  dim3 agrid((NPER + 31) / 32, NB);
  attn3k<<<agrid, 256, 0, stream>>>(qb, kh, vh, o_bf, NPER);
  gemm128<<<(N + 63) / 64, 256, 0, stream>>>(o_bf, w2b, b2, 1.f, (float*)d_out, nullptr, N);
}